// Round 6
// baseline (1212.873 us; speedup 1.0000x reference)
//
#include <hip/hip_runtime.h>
#include <stdint.h>

// Problem constants
#define Bb  8
#define Ss  4096
#define Dd  512
#define DIi 2048
#define Mm  (Bb*Ss)   // 32768 rows

typedef unsigned short u16;
typedef __bf16 bf16x8 __attribute__((ext_vector_type(8)));
typedef float  f32x4  __attribute__((ext_vector_type(4)));

__device__ __forceinline__ float bfu(unsigned int u) {
  return __uint_as_float((u & 0xffffu) << 16);
}
__device__ __forceinline__ u16 f2bu(float f) {
  unsigned int x = __float_as_uint(f);
  return (u16)((x + 0x7fffu + ((x >> 16) & 1u)) >> 16);  // RNE
}

// XCD-chunk remap: 8-panel row-chunks per XCD so A-chunk (2MB @K=512) + B
// fit one XCD's 4MB L2. Requires gridDim.y % 64 == 0 (ours: 128). Bijective.
__device__ __forceinline__ void xcd_remap(int& bx, int& by) {
  const int nx = gridDim.x;
  const int s = by * nx + bx;       // launch-order id (x fastest)
  const int xcd = s & 7;
  const int g = s >> 3;
  const int cpc = nx << 3;          // blocks per 8-panel chunk
  const int cw = g / cpc;           // chunk layer
  const int rem = g % cpc;
  by = cw * 64 + xcd * 8 + rem / nx;
  bx = rem % nx;
}

__global__ __launch_bounds__(256) void zero_f32(float* __restrict__ p, int n) {
  int i = blockIdx.x * 256 + threadIdx.x;
  if (i < n) p[i] = 0.f;
}

__global__ __launch_bounds__(256) void f32_to_bf16_vec(const float* __restrict__ in,
                                                       u16* __restrict__ outp, long n4) {
  long i = (long)blockIdx.x * 256 + threadIdx.x;
  const long st = (long)gridDim.x * 256;
  for (; i < n4; i += st) {
    float4 v = ((const float4*)in)[i];
    ushort4 o;
    o.x = f2bu(v.x); o.y = f2bu(v.y); o.z = f2bu(v.z); o.w = f2bu(v.w);
    ((ushort4*)outp)[i] = o;
  }
}

// batched transpose f32 [K][N] -> bf16 [N][K]; blockIdx.z selects the pair
__global__ void transpose_f32_bf16_z(const float* s0, const float* s1,
                                     const float* s2, const float* s3,
                                     u16* d0, u16* d1, u16* d2, u16* d3,
                                     int K, int N) {
  const float* W; u16* Wt;
  switch (blockIdx.z) {
    case 0:  W = s0; Wt = d0; break;
    case 1:  W = s1; Wt = d1; break;
    case 2:  W = s2; Wt = d2; break;
    default: W = s3; Wt = d3; break;
  }
  __shared__ float t[32][33];
  const int n0 = blockIdx.x * 32, k0 = blockIdx.y * 32;
  const int tx = threadIdx.x, ty = threadIdx.y;  // 32 x 8
#pragma unroll
  for (int i = 0; i < 32; i += 8)
    t[ty + i][tx] = W[(long)(k0 + ty + i) * N + n0 + tx];
  __syncthreads();
#pragma unroll
  for (int i = 0; i < 32; i += 8)
    Wt[(long)(n0 + ty + i) * K + k0 + tx] = f2bu(t[tx][ty + i]);
}

// wob[b][n][k] = woT[n][k] * kv[b][k]   (bf16 out, 8 batch copies of wo^T)
__global__ __launch_bounds__(256) void build_wob(const u16* __restrict__ woT,
                                                 const float* __restrict__ kv,
                                                 u16* __restrict__ wob) {
  const int b = blockIdx.y;
  long i = (long)blockIdx.x * 256 + threadIdx.x;
  const long tot = (long)Dd * DIi / 8;
  if (i >= tot) return;
  const long e = i * 8;
  const int k = (int)(e & (DIi - 1));
  ushort4 w0 = *(const ushort4*)(woT + e);
  ushort4 w1 = *(const ushort4*)(woT + e + 4);
  const float* kvp = kv + (long)b * DIi + k;
  ushort4 o0, o1;
  o0.x = f2bu(bfu(w0.x) * kvp[0]); o0.y = f2bu(bfu(w0.y) * kvp[1]);
  o0.z = f2bu(bfu(w0.z) * kvp[2]); o0.w = f2bu(bfu(w0.w) * kvp[3]);
  o1.x = f2bu(bfu(w1.x) * kvp[4]); o1.y = f2bu(bfu(w1.y) * kvp[5]);
  o1.z = f2bu(bfu(w1.z) * kvp[6]); o1.w = f2bu(bfu(w1.w) * kvp[7]);
  u16* dst = wob + (long)b * Dd * DIi + e;
  *(ushort4*)dst = o0;
  *(ushort4*)(dst + 4) = o1;
}

// kv[b,e] = sum_s P[b,s,e] * rsqrt(nksq[b,s])   (f32 atomics over s-chunks)
__global__ __launch_bounds__(256) void kv_reduce(const u16* __restrict__ P,
                                                 const float* __restrict__ nksq,
                                                 float* __restrict__ kv) {
  const int b  = blockIdx.y;
  const int e0 = blockIdx.x * 1024 + threadIdx.x * 4;
  const int s0 = blockIdx.z * 256;
  const u16* pp = P + ((size_t)(b * Ss + s0)) * DIi + e0;
  const float* nn = nksq + b * Ss + s0;
  float a0 = 0, a1 = 0, a2 = 0, a3 = 0;
  for (int s = 0; s < 256; ++s) {
    const float r = 1.f / fmaxf(sqrtf(nn[s]), 1e-12f);
    ushort4 u = *(const ushort4*)pp;
    a0 += bfu(u.x) * r;
    a1 += bfu(u.y) * r;
    a2 += bfu(u.z) * r;
    a3 += bfu(u.w) * r;
    pp += DIi;
  }
  float* o = kv + (long)b * DIi + e0;
  atomicAdd(o + 0, a0); atomicAdd(o + 1, a1);
  atomicAdd(o + 2, a2); atomicAdd(o + 3, a3);
}

#define GLL(src, dst) \
  __builtin_amdgcn_global_load_lds((const __attribute__((address_space(1))) unsigned int*)(src), \
                                   (__attribute__((address_space(3))) unsigned int*)(dst), 16, 0, 0)

// ============ fused K,V product GEMM (dual-B, BK=32, 96 KB LDS) ============
// acc1 = x@wk tile, acc2 = x@wv tile; store P = bf16(acc1*acc2), atomicAdd
// per-row sum(acc1^2) -> nksq. K=Dd=512, N=DIi=2048 fixed.
__global__ __launch_bounds__(512, 2) void kvp_gemm(
    const u16* __restrict__ A, const u16* __restrict__ B1, const u16* __restrict__ B2,
    u16* __restrict__ P, float* __restrict__ nksq)
{
  __shared__ u16 lds8[49152];   // 96 KB = 2 x (A 16K + B1 16K + B2 16K)
  const int K = Dd, N = DIi;

  int bx = blockIdx.x, by = blockIdx.y;
  xcd_remap(bx, by);
  const int tid = threadIdx.x, lane = tid & 63, wid = tid >> 6;
  const int wr = wid >> 2, wc = wid & 3;     // 2x4 wave grid, wave tile 128x64
  const int l15 = lane & 15, lg = lane >> 4;
  const long bm0 = (long)by * 256, bn0 = (long)bx * 256;
  const int NT = K >> 5;                     // 16 K-tiles of 32

  const u16* pA  = A  + bm0 * K;
  const u16* pB1 = B1 + bn0 * K;
  const u16* pB2 = B2 + bn0 * K;

  // staging decode: chunk c0 = wid*64+lane (j=0), +512 (j=1 -> row+128)
  const int c0   = wid * 64 + lane;
  const int qrow = ((c0 >> 5) << 3) | (c0 & 7);
  const int qcol = ((c0 >> 3) & 3) * 8;

  // quarter layout (bytes): (row>>3)*512 + (col>>3)*128 + (row&7)*16 + (col&7)*2
#define STAGEQ(PTR, TT, QB, BUFB) do {                                      \
    const u16* s_ = (PTR) + (size_t)qrow * K + (TT) * 32 + qcol;            \
    u16* d_ = lds8 + (((BUFB) + (QB) + wid * 1024) >> 1);                   \
    GLL(s_, d_);                                                            \
    GLL(s_ + (size_t)128 * K, d_ + 4096);                                   \
  } while (0)

  // frag bases (u16 units)
  const int fb = (l15 >> 3) * 256 + lg * 64 + (l15 & 7) * 8;
  const int abase  = wr * 4096 + fb;
  const int b1base = 8192 + wc * 2048 + fb;
  const int b2base = 16384 + wc * 2048 + fb;

  f32x4 acc1[8][4] = {};
  f32x4 acc2[8][4] = {};

  // prologue: tile0 (A,B1,B2) + tile1 A
  STAGEQ(pA, 0, 0, 0);
  STAGEQ(pB1, 0, 16384, 0);
  STAGEQ(pB2, 0, 32768, 0);
  STAGEQ(pA, 1, 0, 49152);
  asm volatile("s_waitcnt vmcnt(2)" ::: "memory");
  __builtin_amdgcn_s_barrier();

  for (int t = 0; t < NT; ++t) {
    const int bufb = (t & 1) * 49152;        // bytes
    const int nbufb = bufb ^ 49152;
    const int bu = bufb >> 1;                // u16 units
    bf16x8 aF[8], bF[4];

    // ---- phase 0: A frags + B1 frags; stage B1(t+1); mfma acc1 ----
#pragma unroll
    for (int m = 0; m < 8; ++m) aF[m] = *(const bf16x8*)(lds8 + bu + abase + m * 512);
#pragma unroll
    for (int n = 0; n < 4; ++n) bF[n] = *(const bf16x8*)(lds8 + bu + b1base + n * 512);
    if (t + 1 < NT) STAGEQ(pB1, t + 1, 16384, nbufb);
    __builtin_amdgcn_s_barrier();
    __builtin_amdgcn_s_setprio(1);
#pragma unroll
    for (int m = 0; m < 8; ++m)
#pragma unroll
      for (int n = 0; n < 4; ++n)
        acc1[m][n] = __builtin_amdgcn_mfma_f32_16x16x32_bf16(aF[m], bF[n], acc1[m][n], 0, 0, 0);
    __builtin_amdgcn_s_setprio(0);

    // ---- phase 1: B2 frags; stage B2(t+1); mfma acc2 ----
#pragma unroll
    for (int n = 0; n < 4; ++n) bF[n] = *(const bf16x8*)(lds8 + bu + b2base + n * 512);
    if (t + 1 < NT) STAGEQ(pB2, t + 1, 32768, nbufb);
    __builtin_amdgcn_s_barrier();
    __builtin_amdgcn_s_setprio(1);
#pragma unroll
    for (int m = 0; m < 8; ++m)
#pragma unroll
      for (int n = 0; n < 4; ++n)
        acc2[m][n] = __builtin_amdgcn_mfma_f32_16x16x32_bf16(aF[m], bF[n], acc2[m][n], 0, 0, 0);
    __builtin_amdgcn_s_setprio(0);

    // ---- tile boundary (FIFO: drains A,B1,B2 of t+1; keeps A(t+2)) ----
    if (t + 1 < NT) {
      __builtin_amdgcn_s_barrier();
      if (t + 2 < NT) {
        STAGEQ(pA, t + 2, 0, bufb);
        asm volatile("s_waitcnt vmcnt(2)" ::: "memory");
      } else {
        asm volatile("s_waitcnt vmcnt(0)" ::: "memory");
      }
      __builtin_amdgcn_s_barrier();
    }
  }

  // epilogue: P = bf16(k*v), nksq += k^2 (per-row)
  float sk[32];
#pragma unroll
  for (int i = 0; i < 32; ++i) sk[i] = 0.f;
#pragma unroll
  for (int m = 0; m < 8; ++m) {
    const long row0 = bm0 + wr * 128 + m * 16 + lg * 4;
#pragma unroll
    for (int n = 0; n < 4; ++n) {
      const long col = bn0 + wc * 64 + n * 16 + l15;
#pragma unroll
      for (int r = 0; r < 4; ++r) {
        const float kvl = acc1[m][n][r];
        P[(row0 + r) * N + col] = f2bu(kvl * acc2[m][n][r]);
        sk[m * 4 + r] += kvl * kvl;
      }
    }
  }
#pragma unroll
  for (int i = 0; i < 32; ++i) {
#pragma unroll
    for (int off = 1; off < 16; off <<= 1)
      sk[i] += __shfl_xor(sk[i], off, 64);
  }
  if (l15 == 0) {
#pragma unroll
    for (int m = 0; m < 8; ++m)
#pragma unroll
      for (int r = 0; r < 4; ++r)
        atomicAdd(&nksq[bm0 + wr * 128 + m * 16 + lg * 4 + r], sk[m * 4 + r]);
  }
#undef STAGEQ
}

// =================== 256^2-tile 8-wave pipelined GEMM ===================
enum { G_PROJ = 0, G_WO = 1, G_FFN1 = 2, G_FFN2 = 3 };

template<int MODE>
__global__ __launch_bounds__(512, 2) void gemm8(
    const u16* __restrict__ A, const u16* __restrict__ Bt,
    int N, int K,
    u16* __restrict__ Ybf, float* __restrict__ Yf,
    const u16* __restrict__ resb, const float* __restrict__ bias,
    float* __restrict__ nsq, const float* __restrict__ nsqIn)
{
  __shared__ u16 lds8[65536];   // 128 KB

  int bx = blockIdx.x, by = blockIdx.y;
  xcd_remap(bx, by);
  const int tid  = threadIdx.x;
  const int lane = tid & 63;
  const int wid  = tid >> 6;
  const int wr = wid >> 2, wc = wid & 3;
  const int l15 = lane & 15, lg = lane >> 4;
  const long bm0 = (long)by * 256;
  const long bn0 = (long)bx * 256;
  const int NT = K >> 6;

  const int bq = (int)(bm0 >> 12);
  const u16* pA = A + bm0 * K;
  const u16* pB = Bt + bn0 * K + (MODE == G_WO ? (size_t)bq * Dd * DIi : 0);

  const int rowT = ((tid >> 6) << 3) | (tid & 7);
  const int cc8  = ((tid >> 3) & 7) * 8;

#define STAGE(PTR, LD, H, TT, BUFU, REGU) do {                                  \
    const u16* s0_ = (PTR) + (size_t)((H) * 128 + rowT) * (LD)                  \
                     + (size_t)(TT) * 64 + cc8;                                 \
    u16* d_ = lds8 + (BUFU) + (REGU) + (H) * 8192 + wid * 512;                  \
    GLL(s0_, d_);                                                               \
    GLL(s0_ + (size_t)64 * (LD), d_ + 4096);                                    \
  } while (0)

  const int aoff = (wr * 16384 + (l15 >> 3) * 1024 + lg * 128 + (l15 & 7) * 16) >> 1;
  const int boff = (32768 + (wc >> 1) * 16384 + (wc & 1) * 8192 +
                    (l15 >> 3) * 1024 + lg * 128 + (l15 & 7) * 16) >> 1;
#define LDA(M_, KS_, BU_) (*(const bf16x8*)(lds8 + (BU_) + aoff + (M_) * 1024 + (KS_) * 256))
#define LDB(N_, KS_, BU_) (*(const bf16x8*)(lds8 + (BU_) + boff + (N_) * 1024 + (KS_) * 256))

  f32x4 acc[8][4] = {};

  STAGE(pA, K, 0, 0, 0, 0);
  STAGE(pA, K, 1, 0, 0, 0);
  STAGE(pB, K, 0, 0, 0, 16384);
  STAGE(pB, K, 1, 0, 0, 16384);
  STAGE(pA, K, 0, 1, 32768, 0);
  asm volatile("s_waitcnt vmcnt(2)" ::: "memory");
  __builtin_amdgcn_s_barrier();

  for (int t = 0; t < NT; ++t) {
    const int bufu = (t & 1) * 32768;
    const int nbuf = bufu ^ 32768;
    bf16x8 aF[4], bF[4];

#pragma unroll
    for (int n = 0; n < 4; ++n) bF[n] = LDB(n, 0, bufu);
#pragma unroll
    for (int m = 0; m < 4; ++m) aF[m] = LDA(m, 0, bufu);
    if (t + 1 < NT) STAGE(pA, K, 1, t + 1, nbuf, 0);
    __builtin_amdgcn_s_barrier();
    __builtin_amdgcn_s_setprio(1);
#pragma unroll
    for (int m = 0; m < 4; ++m)
#pragma unroll
      for (int n = 0; n < 4; ++n)
        acc[m][n] = __builtin_amdgcn_mfma_f32_16x16x32_bf16(aF[m], bF[n], acc[m][n], 0, 0, 0);
    __builtin_amdgcn_s_setprio(0);

#pragma unroll
    for (int m = 0; m < 4; ++m) aF[m] = LDA(4 + m, 0, bufu);
    if (t + 1 < NT) STAGE(pB, K, 0, t + 1, nbuf, 16384);
    __builtin_amdgcn_s_barrier();
    __builtin_amdgcn_s_setprio(1);
#pragma unroll
    for (int m = 0; m < 4; ++m)
#pragma unroll
      for (int n = 0; n < 4; ++n)
        acc[4 + m][n] = __builtin_amdgcn_mfma_f32_16x16x32_bf16(aF[m], bF[n], acc[4 + m][n], 0, 0, 0);
    __builtin_amdgcn_s_setprio(0);

#pragma unroll
    for (int n = 0; n < 4; ++n) bF[n] = LDB(n, 1, bufu);
#pragma unroll
    for (int m = 0; m < 4; ++m) aF[m] = LDA(m, 1, bufu);
    if (t + 1 < NT) STAGE(pB, K, 1, t + 1, nbuf, 16384);
    __builtin_amdgcn_s_barrier();
    __builtin_amdgcn_s_setprio(1);
#pragma unroll
    for (int m = 0; m < 4; ++m)
#pragma unroll
      for (int n = 0; n < 4; ++n)
        acc[m][n] = __builtin_amdgcn_mfma_f32_16x16x32_bf16(aF[m], bF[n], acc[m][n], 0, 0, 0);
    __builtin_amdgcn_s_setprio(0);

#pragma unroll
    for (int m = 0; m < 4; ++m) aF[m] = LDA(4 + m, 1, bufu);
    __builtin_amdgcn_s_barrier();
    __builtin_amdgcn_s_setprio(1);
#pragma unroll
    for (int m = 0; m < 4; ++m)
#pragma unroll
      for (int n = 0; n < 4; ++n)
        acc[4 + m][n] = __builtin_amdgcn_mfma_f32_16x16x32_bf16(aF[m], bF[n], acc[4 + m][n], 0, 0, 0);
    __builtin_amdgcn_s_setprio(0);

    if (t + 1 < NT) {
      __builtin_amdgcn_s_barrier();
      if (t + 2 < NT) {
        STAGE(pA, K, 0, t + 2, bufu, 0);
        asm volatile("s_waitcnt vmcnt(2)" ::: "memory");
      } else {
        asm volatile("s_waitcnt vmcnt(0)" ::: "memory");
      }
      __builtin_amdgcn_s_barrier();
    }
  }

  // =================== epilogue ===================
  if constexpr (MODE == G_PROJ) {
    float sk[32];
#pragma unroll
    for (int i = 0; i < 32; ++i) sk[i] = 0.f;
#pragma unroll
    for (int m = 0; m < 8; ++m) {
      const long row0 = bm0 + wr * 128 + m * 16 + lg * 4;
#pragma unroll
      for (int n = 0; n < 4; ++n) {
        const long col = bn0 + wc * 64 + n * 16 + l15;
#pragma unroll
        for (int r = 0; r < 4; ++r) {
          const float v = acc[m][n][r];
          Ybf[(row0 + r) * N + col] = f2bu(v);
          sk[m * 4 + r] += v * v;
        }
      }
    }
#pragma unroll
    for (int i = 0; i < 32; ++i) {
#pragma unroll
      for (int off = 1; off < 16; off <<= 1)
        sk[i] += __shfl_xor(sk[i], off, 64);
    }
    if (l15 == 0) {
#pragma unroll
      for (int m = 0; m < 8; ++m)
#pragma unroll
        for (int r = 0; r < 4; ++r)
          atomicAdd(&nsq[bm0 + wr * 128 + m * 16 + lg * 4 + r], sk[m * 4 + r]);
    }
  } else {
#pragma unroll
    for (int m = 0; m < 8; ++m) {
      const long row0 = bm0 + wr * 128 + m * 16 + lg * 4;
      float rq[4];
      if constexpr (MODE == G_WO) {
#pragma unroll
        for (int r = 0; r < 4; ++r)
          rq[r] = 1.f / fmaxf(sqrtf(nsqIn[row0 + r]), 1e-12f);
      }
#pragma unroll
      for (int n = 0; n < 4; ++n) {
        const long col = bn0 + wc * 64 + n * 16 + l15;
#pragma unroll
        for (int r = 0; r < 4; ++r) {
          const long idx = (row0 + r) * N + col;
          const float v = acc[m][n][r];
          if constexpr (MODE == G_WO) {
            Ybf[idx] = f2bu(v * rq[r] + bfu(resb[idx]));   // resb == Ybf, same idx
          } else if constexpr (MODE == G_FFN1) {
            float o = v + bias[col];
            o = o > 0.f ? o : 0.f;
            Ybf[idx] = f2bu(o);
          } else {  // G_FFN2
            Yf[idx] = v + bias[col] + bfu(resb[idx]);
          }
        }
      }
    }
  }
#undef STAGE
#undef LDA
#undef LDB
}

extern "C" void kernel_launch(void* const* d_in, const int* in_sizes, int n_in,
                              void* d_out, int out_size, void* d_ws, size_t ws_size,
                              hipStream_t stream) {
  const float* x  = (const float*)d_in[0];
  const float* wq = (const float*)d_in[1];
  const float* wk = (const float*)d_in[2];
  const float* wv = (const float*)d_in[3];
  const float* wo = (const float*)d_in[4];
  const float* w1 = (const float*)d_in[5];
  const float* b1 = (const float*)d_in[6];
  const float* w2 = (const float*)d_in[7];
  const float* b2 = (const float*)d_in[8];
  float* out = (float*)d_out;

  // workspace carve-up: ~197 MB peak
  char* p = (char*)d_ws;
  auto take = [&](size_t bytes) {
    char* r = p; p += (bytes + 255) & ~(size_t)255; return r;
  };
  u16*   xb   = (u16*)take((size_t)Mm * Dd * 2);    // x bf16; later attn bf16
  u16*   wkT  = (u16*)take((size_t)DIi * Dd * 2);
  u16*   wqT  = (u16*)take((size_t)DIi * Dd * 2);
  u16*   wvT  = (u16*)take((size_t)DIi * Dd * 2);
  u16*   woT  = (u16*)take((size_t)Dd * DIi * 2);
  u16*   w1T  = (u16*)take((size_t)DIi * Dd * 2);
  u16*   w2T  = (u16*)take((size_t)Dd * DIi * 2);
  u16*   wob  = (u16*)take((size_t)Bb * Dd * DIi * 2);  // 16.8 MB
  u16*   buf1 = (u16*)take((size_t)Mm * DIi * 2);   // P, then Q, then h
  float* nksq = (float*)take((size_t)Mm * 4);       // contiguous with next two
  float* nqsq = (float*)take((size_t)Mm * 4);
  float* kvp  = (float*)take((size_t)Bb * DIi * 4);
  (void)ws_size; (void)in_sizes; (void)n_in; (void)out_size;

  const dim3 tpB(32, 8);

  zero_f32<<<(2 * Mm + Bb * DIi + 255) / 256, 256, 0, stream>>>(nksq, 2 * Mm + Bb * DIi);

  f32_to_bf16_vec<<<2048, 256, 0, stream>>>(x, xb, (long)Mm * Dd / 4);
  transpose_f32_bf16_z<<<dim3(DIi / 32, Dd / 32, 4), tpB, 0, stream>>>(
      wk, wq, wv, w1, wkT, wqT, wvT, w1T, Dd, DIi);
  transpose_f32_bf16_z<<<dim3(Dd / 32, DIi / 32, 2), tpB, 0, stream>>>(
      wo, w2, wo, w2, woT, w2T, woT, w2T, DIi, Dd);

  // P = bf16(K ⊙ V) -> buf1, nksq atomics (one fused dual-B GEMM)
  kvp_gemm<<<dim3(DIi / 256, Mm / 256), 512, 0, stream>>>(xb, wkT, wvT, buf1, nksq);

  // kv[b,e] = sum_s P * rsqrt(nksq)
  kv_reduce<<<dim3(DIi / 1024, Bb, Ss / 256), 256, 0, stream>>>(buf1, nksq, kvp);

  // Q = x@wq -> buf1 (P dead) + nqsq
  gemm8<G_PROJ><<<dim3(DIi / 256, Mm / 256), 512, 0, stream>>>(
      xb, wqT, DIi, Dd, buf1, nullptr, nullptr, nullptr, nqsq, nullptr);

  // wob[b] = woT * kv[b]
  build_wob<<<dim3((Dd * DIi / 8 + 255) / 256, Bb), 256, 0, stream>>>(woT, kvp, wob);

  // attn = (q @ wob[b]) * rsqrt(nqsq) + xb -> bf16 in place of xb
  gemm8<G_WO><<<dim3(Dd / 256, Mm / 256), 512, 0, stream>>>(
      buf1, wob, Dd, DIi, xb, nullptr, xb, nullptr, nullptr, nqsq);

  // h = relu(attn @ w1 + b1) -> buf1
  gemm8<G_FFN1><<<dim3(DIi / 256, Mm / 256), 512, 0, stream>>>(
      xb, w1T, DIi, Dd, buf1, nullptr, nullptr, b1, nullptr, nullptr);

  // out = h @ w2 + b2 + attn
  gemm8<G_FFN2><<<dim3(Dd / 256, Mm / 256), 512, 0, stream>>>(
      buf1, w2T, Dd, DIi, nullptr, out, xb, b2, nullptr, nullptr);
}

// Round 7
// 647.503 us; speedup vs baseline: 1.8732x; 1.8732x over previous
//
#include <hip/hip_runtime.h>
#include <stdint.h>

// Problem constants
#define Bb  8
#define Ss  4096
#define Dd  512
#define DIi 2048
#define Mm  (Bb*Ss)   // 32768 rows

typedef unsigned short u16;
typedef __bf16 bf16x8 __attribute__((ext_vector_type(8)));
typedef float  f32x4  __attribute__((ext_vector_type(4)));

__device__ __forceinline__ float bfu(unsigned int u) {
  return __uint_as_float((u & 0xffffu) << 16);
}
__device__ __forceinline__ u16 f2bu(float f) {
  unsigned int x = __float_as_uint(f);
  return (u16)((x + 0x7fffu + ((x >> 16) & 1u)) >> 16);  // RNE
}

// XCD-chunk remap: 8-panel row-chunks per XCD. Requires gridDim.y % 64 == 0.
__device__ __forceinline__ void xcd_remap(int& bx, int& by) {
  const int nx = gridDim.x;
  const int s = by * nx + bx;
  const int xcd = s & 7;
  const int g = s >> 3;
  const int cpc = nx << 3;
  const int cw = g / cpc;
  const int rem = g % cpc;
  by = cw * 64 + xcd * 8 + rem / nx;
  bx = rem % nx;
}

__global__ __launch_bounds__(256) void zero_f32(float* __restrict__ p, int n) {
  int i = blockIdx.x * 256 + threadIdx.x;
  if (i < n) p[i] = 0.f;
}

__global__ __launch_bounds__(256) void f32_to_bf16_vec(const float* __restrict__ in,
                                                       u16* __restrict__ outp, long n4) {
  long i = (long)blockIdx.x * 256 + threadIdx.x;
  const long st = (long)gridDim.x * 256;
  for (; i < n4; i += st) {
    float4 v = ((const float4*)in)[i];
    ushort4 o;
    o.x = f2bu(v.x); o.y = f2bu(v.y); o.z = f2bu(v.z); o.w = f2bu(v.w);
    ((ushort4*)outp)[i] = o;
  }
}

// batched transpose f32 [K][N] -> bf16 [N][K]; blockIdx.z selects the pair
__global__ void transpose_f32_bf16_z(const float* s0, const float* s1,
                                     const float* s2, const float* s3,
                                     u16* d0, u16* d1, u16* d2, u16* d3,
                                     int K, int N) {
  const float* W; u16* Wt;
  switch (blockIdx.z) {
    case 0:  W = s0; Wt = d0; break;
    case 1:  W = s1; Wt = d1; break;
    case 2:  W = s2; Wt = d2; break;
    default: W = s3; Wt = d3; break;
  }
  __shared__ float t[32][33];
  const int n0 = blockIdx.x * 32, k0 = blockIdx.y * 32;
  const int tx = threadIdx.x, ty = threadIdx.y;  // 32 x 8
#pragma unroll
  for (int i = 0; i < 32; i += 8)
    t[ty + i][tx] = W[(long)(k0 + ty + i) * N + n0 + tx];
  __syncthreads();
#pragma unroll
  for (int i = 0; i < 32; i += 8)
    Wt[(long)(n0 + ty + i) * K + k0 + tx] = f2bu(t[tx][ty + i]);
}

// wob[b][n][k] = woT[n][k] * kv[b][k]   (bf16 out, 8 batch copies of wo^T)
__global__ __launch_bounds__(256) void build_wob(const u16* __restrict__ woT,
                                                 const float* __restrict__ kv,
                                                 u16* __restrict__ wob) {
  const int b = blockIdx.y;
  long i = (long)blockIdx.x * 256 + threadIdx.x;
  const long tot = (long)Dd * DIi / 8;
  if (i >= tot) return;
  const long e = i * 8;
  const int k = (int)(e & (DIi - 1));
  ushort4 w0 = *(const ushort4*)(woT + e);
  ushort4 w1 = *(const ushort4*)(woT + e + 4);
  const float* kvp = kv + (long)b * DIi + k;
  ushort4 o0, o1;
  o0.x = f2bu(bfu(w0.x) * kvp[0]); o0.y = f2bu(bfu(w0.y) * kvp[1]);
  o0.z = f2bu(bfu(w0.z) * kvp[2]); o0.w = f2bu(bfu(w0.w) * kvp[3]);
  o1.x = f2bu(bfu(w1.x) * kvp[4]); o1.y = f2bu(bfu(w1.y) * kvp[5]);
  o1.z = f2bu(bfu(w1.z) * kvp[6]); o1.w = f2bu(bfu(w1.w) * kvp[7]);
  u16* dst = wob + (long)b * Dd * DIi + e;
  *(ushort4*)dst = o0;
  *(ushort4*)(dst + 4) = o1;
}

// kv[b,e] = sum_s P[b,s,e] * rsqrt(nksq[b,s])   (f32 atomics over s-chunks)
__global__ __launch_bounds__(256) void kv_reduce(const u16* __restrict__ P,
                                                 const float* __restrict__ nksq,
                                                 float* __restrict__ kv) {
  const int b  = blockIdx.y;
  const int e0 = blockIdx.x * 1024 + threadIdx.x * 4;
  const int s0 = blockIdx.z * 256;
  const u16* pp = P + ((size_t)(b * Ss + s0)) * DIi + e0;
  const float* nn = nksq + b * Ss + s0;
  float a0 = 0, a1 = 0, a2 = 0, a3 = 0;
  for (int s = 0; s < 256; ++s) {
    const float r = 1.f / fmaxf(sqrtf(nn[s]), 1e-12f);
    ushort4 u = *(const ushort4*)pp;
    a0 += bfu(u.x) * r;
    a1 += bfu(u.y) * r;
    a2 += bfu(u.z) * r;
    a3 += bfu(u.w) * r;
    pp += DIi;
  }
  float* o = kv + (long)b * DIi + e0;
  atomicAdd(o + 0, a0); atomicAdd(o + 1, a1);
  atomicAdd(o + 2, a2); atomicAdd(o + 3, a3);
}

#define GLL(src, dst) \
  __builtin_amdgcn_global_load_lds((const __attribute__((address_space(1))) unsigned int*)(src), \
                                   (__attribute__((address_space(3))) unsigned int*)(dst), 16, 0, 0)

// ===== fused K,V product GEMM v2: BM=128, wave tile 64x64, no spill =====
// acc1 = x@wk tile, acc2 = x@wv tile; P = bf16(acc1*acc2); nksq += acc1^2.
// LDS per buffer: A 8KB + B1 16KB + B2 16KB = 40KB; dbuf 80KB -> 2 blk/CU.
// Accumulators: 2 x 4x4 x f32x4 = 128 VGPR (fits 256 cap at 2 waves/SIMD).
__global__ __launch_bounds__(512, 2) void kvp_gemm(
    const u16* __restrict__ A, const u16* __restrict__ B1, const u16* __restrict__ B2,
    u16* __restrict__ P, float* __restrict__ nksq)
{
  __shared__ u16 lds8[40960];   // 80 KB
  const int K = Dd, N = DIi;

  int bx = blockIdx.x, by = blockIdx.y;
  xcd_remap(bx, by);
  const int tid = threadIdx.x, lane = tid & 63, wid = tid >> 6;
  const int wr = wid >> 2, wc = wid & 3;     // 2x4 wave grid; wave tile 64x64
  const int l15 = lane & 15, lg = lane >> 4;
  const long bm0 = (long)by * 128, bn0 = (long)bx * 256;
  const int NT = K >> 5;                     // 16 K-tiles of 32

  const u16* pA  = A  + bm0 * K;
  const u16* pB1 = B1 + bn0 * K;
  const u16* pB2 = B2 + bn0 * K;

  // staging decode: chunk c = tid (A: 512 chunks; B: 1024 = tid and tid+512)
  // quarter layout byte = (row>>3)*512 + colchunk*128 + (row&7)*16  == c*16
  const int qrow = ((tid >> 5) << 3) | (tid & 7);   // 0..127
  const int qcol = ((tid >> 3) & 3) * 8;            // 0,8,16,24

  // A stage: 1 GLL (8 KB); B stage: 2 GLL (16 KB, rows +128 at +8192B)
#define STAGEA(TT, BUFB) do {                                               \
    const u16* s_ = pA + (size_t)qrow * K + (TT) * 32 + qcol;               \
    GLL(s_, (u16*)((char*)lds8 + (BUFB) + tid * 16));                       \
  } while (0)
#define STAGEB(PTR, TT, QB, BUFB) do {                                      \
    const u16* s_ = (PTR) + (size_t)qrow * K + (TT) * 32 + qcol;            \
    u16* d_ = (u16*)((char*)lds8 + (BUFB) + (QB) + tid * 16);               \
    GLL(s_, d_);                                                            \
    GLL(s_ + (size_t)128 * K, (u16*)((char*)d_ + 8192));                    \
  } while (0)

  // frag base offsets (bytes, within buffer)
  const int fb = (l15 >> 3) * 512 + lg * 128 + (l15 & 7) * 16;
  const int abyte  = wr * 4096 + fb;                // + m*1024
  const int b1byte = 8192 + wc * 4096 + fb;         // + n*1024
  const int b2byte = 24576 + wc * 4096 + fb;

  f32x4 acc1[4][4] = {};
  f32x4 acc2[4][4] = {};

  // prologue: tile0 (A,B1,B2) + tile1 A   -> 6 loads, keep A(1) in flight
  STAGEA(0, 0);
  STAGEB(pB1, 0, 8192, 0);
  STAGEB(pB2, 0, 24576, 0);
  STAGEA(1, 40960);
  asm volatile("s_waitcnt vmcnt(1)" ::: "memory");
  __builtin_amdgcn_s_barrier();

  for (int t = 0; t < NT; ++t) {
    const int bufb = (t & 1) * 40960;
    const int nbufb = bufb ^ 40960;
    bf16x8 aF[4], bF[4];

    // ---- phase 0: A + B1 frags; stage B1(t+1); mfma acc1 ----
#pragma unroll
    for (int m = 0; m < 4; ++m)
      aF[m] = *(const bf16x8*)((const char*)lds8 + bufb + abyte + m * 1024);
#pragma unroll
    for (int n = 0; n < 4; ++n)
      bF[n] = *(const bf16x8*)((const char*)lds8 + bufb + b1byte + n * 1024);
    if (t + 1 < NT) STAGEB(pB1, t + 1, 8192, nbufb);
    __builtin_amdgcn_s_barrier();
    __builtin_amdgcn_s_setprio(1);
#pragma unroll
    for (int m = 0; m < 4; ++m)
#pragma unroll
      for (int n = 0; n < 4; ++n)
        acc1[m][n] = __builtin_amdgcn_mfma_f32_16x16x32_bf16(aF[m], bF[n], acc1[m][n], 0, 0, 0);
    __builtin_amdgcn_s_setprio(0);

    // ---- phase 1: B2 frags; stage B2(t+1); mfma acc2 ----
#pragma unroll
    for (int n = 0; n < 4; ++n)
      bF[n] = *(const bf16x8*)((const char*)lds8 + bufb + b2byte + n * 1024);
    if (t + 1 < NT) STAGEB(pB2, t + 1, 24576, nbufb);
    __builtin_amdgcn_s_barrier();
    __builtin_amdgcn_s_setprio(1);
#pragma unroll
    for (int m = 0; m < 4; ++m)
#pragma unroll
      for (int n = 0; n < 4; ++n)
        acc2[m][n] = __builtin_amdgcn_mfma_f32_16x16x32_bf16(aF[m], bF[n], acc2[m][n], 0, 0, 0);
    __builtin_amdgcn_s_setprio(0);

    // ---- tile boundary (FIFO: A(t+1),B1(t+1),B2(t+1) drain; A(t+2) stays) ----
    if (t + 1 < NT) {
      __builtin_amdgcn_s_barrier();
      if (t + 2 < NT) {
        STAGEA(t + 2, bufb);
        asm volatile("s_waitcnt vmcnt(1)" ::: "memory");
      } else {
        asm volatile("s_waitcnt vmcnt(0)" ::: "memory");
      }
      __builtin_amdgcn_s_barrier();
    }
  }

  // epilogue: P = bf16(k*v), nksq += k^2 (per-row)
  float sk[16];
#pragma unroll
  for (int i = 0; i < 16; ++i) sk[i] = 0.f;
#pragma unroll
  for (int m = 0; m < 4; ++m) {
    const long row0 = bm0 + wr * 64 + m * 16 + lg * 4;
#pragma unroll
    for (int n = 0; n < 4; ++n) {
      const long col = bn0 + wc * 64 + n * 16 + l15;
#pragma unroll
      for (int r = 0; r < 4; ++r) {
        const float kvl = acc1[m][n][r];
        P[(row0 + r) * N + col] = f2bu(kvl * acc2[m][n][r]);
        sk[m * 4 + r] += kvl * kvl;
      }
    }
  }
#pragma unroll
  for (int i = 0; i < 16; ++i) {
#pragma unroll
    for (int off = 1; off < 16; off <<= 1)
      sk[i] += __shfl_xor(sk[i], off, 64);
  }
  if (l15 == 0) {
#pragma unroll
    for (int m = 0; m < 4; ++m)
#pragma unroll
      for (int r = 0; r < 4; ++r)
        atomicAdd(&nksq[bm0 + wr * 64 + m * 16 + lg * 4 + r], sk[m * 4 + r]);
  }
#undef STAGEA
#undef STAGEB
}

// =================== 256^2-tile 8-wave pipelined GEMM ===================
enum { G_PROJ = 0, G_WO = 1, G_FFN1 = 2, G_FFN2 = 3 };

template<int MODE>
__global__ __launch_bounds__(512, 2) void gemm8(
    const u16* __restrict__ A, const u16* __restrict__ Bt,
    int N, int K,
    u16* __restrict__ Ybf, float* __restrict__ Yf,
    const u16* __restrict__ resb, const float* __restrict__ bias,
    float* __restrict__ nsq, const float* __restrict__ nsqIn)
{
  __shared__ u16 lds8[65536];   // 128 KB

  int bx = blockIdx.x, by = blockIdx.y;
  xcd_remap(bx, by);
  const int tid  = threadIdx.x;
  const int lane = tid & 63;
  const int wid  = tid >> 6;
  const int wr = wid >> 2, wc = wid & 3;
  const int l15 = lane & 15, lg = lane >> 4;
  const long bm0 = (long)by * 256;
  const long bn0 = (long)bx * 256;
  const int NT = K >> 6;

  const int bq = (int)(bm0 >> 12);
  const u16* pA = A + bm0 * K;
  const u16* pB = Bt + bn0 * K + (MODE == G_WO ? (size_t)bq * Dd * DIi : 0);

  const int rowT = ((tid >> 6) << 3) | (tid & 7);
  const int cc8  = ((tid >> 3) & 7) * 8;

#define STAGE(PTR, LD, H, TT, BUFU, REGU) do {                                  \
    const u16* s0_ = (PTR) + (size_t)((H) * 128 + rowT) * (LD)                  \
                     + (size_t)(TT) * 64 + cc8;                                 \
    u16* d_ = lds8 + (BUFU) + (REGU) + (H) * 8192 + wid * 512;                  \
    GLL(s0_, d_);                                                               \
    GLL(s0_ + (size_t)64 * (LD), d_ + 4096);                                    \
  } while (0)

  const int aoff = (wr * 16384 + (l15 >> 3) * 1024 + lg * 128 + (l15 & 7) * 16) >> 1;
  const int boff = (32768 + (wc >> 1) * 16384 + (wc & 1) * 8192 +
                    (l15 >> 3) * 1024 + lg * 128 + (l15 & 7) * 16) >> 1;
#define LDA(M_, KS_, BU_) (*(const bf16x8*)(lds8 + (BU_) + aoff + (M_) * 1024 + (KS_) * 256))
#define LDB(N_, KS_, BU_) (*(const bf16x8*)(lds8 + (BU_) + boff + (N_) * 1024 + (KS_) * 256))

  f32x4 acc[8][4] = {};

  STAGE(pA, K, 0, 0, 0, 0);
  STAGE(pA, K, 1, 0, 0, 0);
  STAGE(pB, K, 0, 0, 0, 16384);
  STAGE(pB, K, 1, 0, 0, 16384);
  STAGE(pA, K, 0, 1, 32768, 0);
  asm volatile("s_waitcnt vmcnt(2)" ::: "memory");
  __builtin_amdgcn_s_barrier();

  for (int t = 0; t < NT; ++t) {
    const int bufu = (t & 1) * 32768;
    const int nbuf = bufu ^ 32768;
    bf16x8 aF[4], bF[4];

#pragma unroll
    for (int n = 0; n < 4; ++n) bF[n] = LDB(n, 0, bufu);
#pragma unroll
    for (int m = 0; m < 4; ++m) aF[m] = LDA(m, 0, bufu);
    if (t + 1 < NT) STAGE(pA, K, 1, t + 1, nbuf, 0);
    __builtin_amdgcn_s_barrier();
    __builtin_amdgcn_s_setprio(1);
#pragma unroll
    for (int m = 0; m < 4; ++m)
#pragma unroll
      for (int n = 0; n < 4; ++n)
        acc[m][n] = __builtin_amdgcn_mfma_f32_16x16x32_bf16(aF[m], bF[n], acc[m][n], 0, 0, 0);
    __builtin_amdgcn_s_setprio(0);

#pragma unroll
    for (int m = 0; m < 4; ++m) aF[m] = LDA(4 + m, 0, bufu);
    if (t + 1 < NT) STAGE(pB, K, 0, t + 1, nbuf, 16384);
    __builtin_amdgcn_s_barrier();
    __builtin_amdgcn_s_setprio(1);
#pragma unroll
    for (int m = 0; m < 4; ++m)
#pragma unroll
      for (int n = 0; n < 4; ++n)
        acc[4 + m][n] = __builtin_amdgcn_mfma_f32_16x16x32_bf16(aF[m], bF[n], acc[4 + m][n], 0, 0, 0);
    __builtin_amdgcn_s_setprio(0);

#pragma unroll
    for (int n = 0; n < 4; ++n) bF[n] = LDB(n, 1, bufu);
#pragma unroll
    for (int m = 0; m < 4; ++m) aF[m] = LDA(m, 1, bufu);
    if (t + 1 < NT) STAGE(pB, K, 1, t + 1, nbuf, 16384);
    __builtin_amdgcn_s_barrier();
    __builtin_amdgcn_s_setprio(1);
#pragma unroll
    for (int m = 0; m < 4; ++m)
#pragma unroll
      for (int n = 0; n < 4; ++n)
        acc[m][n] = __builtin_amdgcn_mfma_f32_16x16x32_bf16(aF[m], bF[n], acc[m][n], 0, 0, 0);
    __builtin_amdgcn_s_setprio(0);

#pragma unroll
    for (int m = 0; m < 4; ++m) aF[m] = LDA(4 + m, 1, bufu);
    __builtin_amdgcn_s_barrier();
    __builtin_amdgcn_s_setprio(1);
#pragma unroll
    for (int m = 0; m < 4; ++m)
#pragma unroll
      for (int n = 0; n < 4; ++n)
        acc[4 + m][n] = __builtin_amdgcn_mfma_f32_16x16x32_bf16(aF[m], bF[n], acc[4 + m][n], 0, 0, 0);
    __builtin_amdgcn_s_setprio(0);

    if (t + 1 < NT) {
      __builtin_amdgcn_s_barrier();
      if (t + 2 < NT) {
        STAGE(pA, K, 0, t + 2, bufu, 0);
        asm volatile("s_waitcnt vmcnt(2)" ::: "memory");
      } else {
        asm volatile("s_waitcnt vmcnt(0)" ::: "memory");
      }
      __builtin_amdgcn_s_barrier();
    }
  }

  // =================== epilogue ===================
  if constexpr (MODE == G_PROJ) {
    float sk[32];
#pragma unroll
    for (int i = 0; i < 32; ++i) sk[i] = 0.f;
#pragma unroll
    for (int m = 0; m < 8; ++m) {
      const long row0 = bm0 + wr * 128 + m * 16 + lg * 4;
#pragma unroll
      for (int n = 0; n < 4; ++n) {
        const long col = bn0 + wc * 64 + n * 16 + l15;
#pragma unroll
        for (int r = 0; r < 4; ++r) {
          const float v = acc[m][n][r];
          Ybf[(row0 + r) * N + col] = f2bu(v);
          sk[m * 4 + r] += v * v;
        }
      }
    }
#pragma unroll
    for (int i = 0; i < 32; ++i) {
#pragma unroll
      for (int off = 1; off < 16; off <<= 1)
        sk[i] += __shfl_xor(sk[i], off, 64);
    }
    if (l15 == 0) {
#pragma unroll
      for (int m = 0; m < 8; ++m)
#pragma unroll
        for (int r = 0; r < 4; ++r)
          atomicAdd(&nsq[bm0 + wr * 128 + m * 16 + lg * 4 + r], sk[m * 4 + r]);
    }
  } else {
#pragma unroll
    for (int m = 0; m < 8; ++m) {
      const long row0 = bm0 + wr * 128 + m * 16 + lg * 4;
      float rq[4];
      if constexpr (MODE == G_WO) {
#pragma unroll
        for (int r = 0; r < 4; ++r)
          rq[r] = 1.f / fmaxf(sqrtf(nsqIn[row0 + r]), 1e-12f);
      }
#pragma unroll
      for (int n = 0; n < 4; ++n) {
        const long col = bn0 + wc * 64 + n * 16 + l15;
#pragma unroll
        for (int r = 0; r < 4; ++r) {
          const long idx = (row0 + r) * N + col;
          const float v = acc[m][n][r];
          if constexpr (MODE == G_WO) {
            Ybf[idx] = f2bu(v * rq[r] + bfu(resb[idx]));   // resb == Ybf, same idx
          } else if constexpr (MODE == G_FFN1) {
            float o = v + bias[col];
            o = o > 0.f ? o : 0.f;
            Ybf[idx] = f2bu(o);
          } else {  // G_FFN2
            Yf[idx] = v + bias[col] + bfu(resb[idx]);
          }
        }
      }
    }
  }
#undef STAGE
#undef LDA
#undef LDB
}

extern "C" void kernel_launch(void* const* d_in, const int* in_sizes, int n_in,
                              void* d_out, int out_size, void* d_ws, size_t ws_size,
                              hipStream_t stream) {
  const float* x  = (const float*)d_in[0];
  const float* wq = (const float*)d_in[1];
  const float* wk = (const float*)d_in[2];
  const float* wv = (const float*)d_in[3];
  const float* wo = (const float*)d_in[4];
  const float* w1 = (const float*)d_in[5];
  const float* b1 = (const float*)d_in[6];
  const float* w2 = (const float*)d_in[7];
  const float* b2 = (const float*)d_in[8];
  float* out = (float*)d_out;

  // workspace carve-up: ~197 MB peak
  char* p = (char*)d_ws;
  auto take = [&](size_t bytes) {
    char* r = p; p += (bytes + 255) & ~(size_t)255; return r;
  };
  u16*   xb   = (u16*)take((size_t)Mm * Dd * 2);    // x bf16; later attn bf16
  u16*   wkT  = (u16*)take((size_t)DIi * Dd * 2);
  u16*   wqT  = (u16*)take((size_t)DIi * Dd * 2);
  u16*   wvT  = (u16*)take((size_t)DIi * Dd * 2);
  u16*   woT  = (u16*)take((size_t)Dd * DIi * 2);
  u16*   w1T  = (u16*)take((size_t)DIi * Dd * 2);
  u16*   w2T  = (u16*)take((size_t)Dd * DIi * 2);
  u16*   wob  = (u16*)take((size_t)Bb * Dd * DIi * 2);  // 16.8 MB
  u16*   buf1 = (u16*)take((size_t)Mm * DIi * 2);   // P, then Q, then h
  float* nksq = (float*)take((size_t)Mm * 4);       // contiguous with next two
  float* nqsq = (float*)take((size_t)Mm * 4);
  float* kvp  = (float*)take((size_t)Bb * DIi * 4);
  (void)ws_size; (void)in_sizes; (void)n_in; (void)out_size;

  const dim3 tpB(32, 8);

  zero_f32<<<(2 * Mm + Bb * DIi + 255) / 256, 256, 0, stream>>>(nksq, 2 * Mm + Bb * DIi);

  f32_to_bf16_vec<<<2048, 256, 0, stream>>>(x, xb, (long)Mm * Dd / 4);
  transpose_f32_bf16_z<<<dim3(DIi / 32, Dd / 32, 4), tpB, 0, stream>>>(
      wk, wq, wv, w1, wkT, wqT, wvT, w1T, Dd, DIi);
  transpose_f32_bf16_z<<<dim3(Dd / 32, DIi / 32, 2), tpB, 0, stream>>>(
      wo, w2, wo, w2, woT, w2T, woT, w2T, DIi, Dd);

  // P = bf16(K ⊙ V) -> buf1, nksq atomics (fused dual-B GEMM, BM=128)
  kvp_gemm<<<dim3(DIi / 256, Mm / 128), 512, 0, stream>>>(xb, wkT, wvT, buf1, nksq);

  // kv[b,e] = sum_s P * rsqrt(nksq)
  kv_reduce<<<dim3(DIi / 1024, Bb, Ss / 256), 256, 0, stream>>>(buf1, nksq, kvp);

  // Q = x@wq -> buf1 (P dead) + nqsq
  gemm8<G_PROJ><<<dim3(DIi / 256, Mm / 256), 512, 0, stream>>>(
      xb, wqT, DIi, Dd, buf1, nullptr, nullptr, nullptr, nqsq, nullptr);

  // wob[b] = woT * kv[b]
  build_wob<<<dim3((Dd * DIi / 8 + 255) / 256, Bb), 256, 0, stream>>>(woT, kvp, wob);

  // attn = (q @ wob[b]) * rsqrt(nqsq) + xb -> bf16 in place of xb
  gemm8<G_WO><<<dim3(Dd / 256, Mm / 256), 512, 0, stream>>>(
      buf1, wob, Dd, DIi, xb, nullptr, xb, nullptr, nullptr, nqsq);

  // h = relu(attn @ w1 + b1) -> buf1
  gemm8<G_FFN1><<<dim3(DIi / 256, Mm / 256), 512, 0, stream>>>(
      xb, w1T, DIi, Dd, buf1, nullptr, nullptr, b1, nullptr, nullptr);

  // out = h @ w2 + b2 + attn
  gemm8<G_FFN2><<<dim3(Dd / 256, Mm / 256), 512, 0, stream>>>(
      buf1, w2T, Dd, DIi, nullptr, out, xb, b2, nullptr, nullptr);
}